// Round 18
// baseline (404.908 us; speedup 1.0000x reference)
//
#include <hip/hip_runtime.h>
#include <hip/hip_bf16.h>

#define U_N 200000
#define I_N 100000
#define G_N 10000
#define B_N 8192
#define NHG (U_N + G_N)   /* 210000 */
#define GG_K 10000
#define GG_STRIPES 157    /* ceil(10000/64) row stripes */
#define GG_SPLIT 8
#define GG_SC_TOT 79      /* ceil(10000/128) super-chunks */
#define GG_KC4 316        /* Bfrag kc count = 4*GG_SC_TOT */
#define ROWSTR 136        /* LDS row stride in bf16: 128 + 8 pad */

#define BUCK_SHIFT 8
#define BUCK_ROWS 256
#define NBUCK 821         /* ceil(NHG/256) */
#define ACHUNK 12288      /* edges per partition block */

typedef __attribute__((ext_vector_type(8))) short bf16x8;
typedef __attribute__((ext_vector_type(4))) float f32x4;
typedef __attribute__((ext_vector_type(8))) float f32x8;
typedef __attribute__((ext_vector_type(8))) unsigned short us8;

static __device__ __forceinline__ float sigmoidf_(float x) {
    return 1.0f / (1.0f + __expf(-x));
}

// f32 -> bf16 bits, round-to-nearest-even
static __device__ __forceinline__ unsigned bfc(float x) {
    unsigned u = __float_as_uint(x);
    return (u + 0x7fffu + ((u >> 16) & 1u)) >> 16;
}
static __device__ __forceinline__ float bsf(unsigned short u) {
    return __uint_as_float((unsigned)u << 16);
}

// ================= PHASE 1: bfrag + cursor init =================
__global__ void k_phase1(const float* __restrict__ ge, short* __restrict__ Bfrag,
                         int* __restrict__ cursor, int cap, int bfB) {
    int bx = blockIdx.x;
    if (bx < bfB) {
        int t = bx * 256 + threadIdx.x;  // < 316*4*64 exactly
        int l = t & 63;
        int ct = (t >> 6) & 3;
        int kc = t >> 8;
        int j = ct * 16 + (l & 15);
        int kb = kc * 32 + (l >> 4) * 8;
        bf16x8 pack;
#pragma unroll
        for (int e = 0; e < 8; ++e) {
            int k = kb + e;
            float f = (k < GG_K) ? ge[(size_t)k * 64 + j] : 0.f;
            pack[e] = (short)bfc(f);
        }
        *(bf16x8*)(Bfrag + (size_t)t * 8) = pack;
        return;
    }
    int b = (bx - bfB) * 256 + threadIdx.x;
    if (b < NBUCK) cursor[b] = b * cap;
}

// ================= PHASE 2: bscatter || gg_mfma(LDS-staged) || cvt || inits ==========

static __device__ __forceinline__ void bscatter_body(const int* __restrict__ rows,
                                                     const int* __restrict__ cols,
                                                     const float* __restrict__ vals,
                                                     int* __restrict__ cursor,
                                                     int2* __restrict__ bpair,
                                                     int nE, int cap, int blk) {
    __shared__ int h[NBUCK];
    __shared__ int base[NBUCK];
    for (int i = threadIdx.x; i < NBUCK; i += 256) h[i] = 0;
    __syncthreads();
    int s = blk * ACHUNK;
    int end = s + ACHUNK; if (end > nE) end = nE;
    for (int e = s + threadIdx.x; e < end; e += 256)
        atomicAdd(&h[rows[e] >> BUCK_SHIFT], 1);
    __syncthreads();
    for (int i = threadIdx.x; i < NBUCK; i += 256) {
        int c = h[i];
        base[i] = c ? atomicAdd(&cursor[i], c) : 0;
        h[i] = 0;
    }
    __syncthreads();
    for (int e = s + threadIdx.x; e < end; e += 256) {
        int r = rows[e];
        int b = r >> BUCK_SHIFT;
        int pos = base[b] + atomicAdd(&h[b], 1);
        if (pos < (b + 1) * cap)
            bpair[pos] = make_int2(((r & (BUCK_ROWS - 1)) << 24) | cols[e],
                                   __float_as_int(vals[e]));
    }
}

// gg with LDS-staged A: contiguous 512B global reads per 32-lane group.
static __device__ __forceinline__ void gg_mfma_body(const float* __restrict__ A,
                                                    const short* __restrict__ Bfrag,
                                                    float* __restrict__ part, int blk) {
    __shared__ short lds_a[64 * ROWSTR];  // 17408 B
    const int stripe = blk % GG_STRIPES;
    const int ks = blk / GG_STRIPES;            // 0..7
    const int sc0 = ks * 10;
    const int sc1 = (ks == 7) ? GG_SC_TOT : sc0 + 10;
    const int tid = threadIdx.x;
    const int w = tid >> 6, l = tid & 63;
    const int r0w = stripe * 64 + w * 16;
    const int srow = tid >> 5;                  // 0..7
    const int scol = (tid & 31) * 4;            // float offset within 128
    f32x4 acc0 = {0.f, 0.f, 0.f, 0.f}, acc1 = acc0, acc2 = acc0, acc3 = acc0;
    for (int sc = sc0; sc < sc1; ++sc) {
        __syncthreads();
#pragma unroll
        for (int pass = 0; pass < 8; ++pass) {
            int rl = pass * 8 + srow;
            int rg = stripe * 64 + rl; if (rg > GG_K - 1) rg = GG_K - 1;
            int kg = sc * 128 + scol;           // multiple of 4; no f4 straddle at 10000
            float4 a = {0.f, 0.f, 0.f, 0.f};
            if (kg < GG_K) a = *(const float4*)(A + (size_t)rg * GG_K + kg);
            ushort4 o;
            o.x = (unsigned short)bfc(a.x); o.y = (unsigned short)bfc(a.y);
            o.z = (unsigned short)bfc(a.z); o.w = (unsigned short)bfc(a.w);
            *(ushort4*)(lds_a + rl * ROWSTR + scol) = o;
        }
        __syncthreads();
#pragma unroll
        for (int q = 0; q < 4; ++q) {
            int kc = sc * 4 + q;
            bf16x8 af = *(const bf16x8*)(lds_a + (w * 16 + (l & 15)) * ROWSTR
                                         + q * 32 + (l >> 4) * 8);
            const bf16x8* bp = (const bf16x8*)(Bfrag + (size_t)kc * 4 * 64 * 8);
            bf16x8 b0 = bp[0 * 64 + l];
            bf16x8 b1 = bp[1 * 64 + l];
            bf16x8 b2 = bp[2 * 64 + l];
            bf16x8 b3 = bp[3 * 64 + l];
            acc0 = __builtin_amdgcn_mfma_f32_16x16x32_bf16(af, b0, acc0, 0, 0, 0);
            acc1 = __builtin_amdgcn_mfma_f32_16x16x32_bf16(af, b1, acc1, 0, 0, 0);
            acc2 = __builtin_amdgcn_mfma_f32_16x16x32_bf16(af, b2, acc2, 0, 0, 0);
            acc3 = __builtin_amdgcn_mfma_f32_16x16x32_bf16(af, b3, acc3, 0, 0, 0);
        }
    }
    float* po = part + (size_t)ks * GG_K * 64;
    const int orow0 = r0w + (l >> 4) * 4;
    const int ocol = l & 15;
#pragma unroll
    for (int reg = 0; reg < 4; ++reg) {
        int orow = orow0 + reg;
        if (orow < GG_K) {
            float* q = po + (size_t)orow * 64 + ocol;
            q[0]  = acc0[reg];
            q[16] = acc1[reg];
            q[32] = acc2[reg];
            q[48] = acc3[reg];
        }
    }
}

// segments: [0,bsB) bscatter | [+ggB) gg | [+cvtB) cvt | [+uaB) ua init
//         | [+gaB) grp_acc init | gi zero
__global__ __launch_bounds__(256) void k_phase2(
    const int* __restrict__ rows, const int* __restrict__ cols,
    const float* __restrict__ vals, int* __restrict__ cursor,
    int2* __restrict__ bpair, int nE, int cap,
    const float* __restrict__ A, const short* __restrict__ Bfrag,
    float* __restrict__ part,
    const float4* __restrict__ ue4, const float4* __restrict__ ge4,
    ushort4* __restrict__ out4, const int* __restrict__ ui,
    float* __restrict__ ua, float* __restrict__ grp_acc, float* __restrict__ gi_out,
    int bsB, int ggB, int cvtB, int uaB, int gaB) {
    int bx = blockIdx.x;
    if (bx < bsB) { bscatter_body(rows, cols, vals, cursor, bpair, nE, cap, bx); return; }
    bx -= bsB;
    if (bx < ggB) { gg_mfma_body(A, Bfrag, part, bx); return; }
    bx -= ggB;
    if (bx < cvtB) {
        int i = bx * 256 + threadIdx.x;  // < NHG*16 exactly
        float4 f = (i < U_N * 16) ? ue4[i] : ge4[i - U_N * 16];
        ushort4 o;
        o.x = (unsigned short)bfc(f.x);
        o.y = (unsigned short)bfc(f.y);
        o.z = (unsigned short)bfc(f.z);
        o.w = (unsigned short)bfc(f.w);
        out4[i] = o;
        return;
    }
    bx -= cvtB;
    if (bx < uaB) {
        int idx = bx * 256 + threadIdx.x;  // < B_N*64
        int b = idx >> 6, d = idx & 63;
        ua[idx] = ((const float*)ue4)[(size_t)ui[b] * 64 + d];
        return;
    }
    bx -= uaB;
    if (bx < gaB) {
        int idx = bx * 256 + threadIdx.x;  // < G_N*64
        grp_acc[idx] = ((const float*)ge4)[idx];
        return;
    }
    bx -= gaB;
    int idx = bx * 256 + threadIdx.x;
    gi_out[idx] = 0.f;
}

// ================= PHASE 3: bcsr only =================

__global__ __launch_bounds__(256) void k_phase3(const int* __restrict__ cursor,
                                                const int2* __restrict__ bpair,
                                                int2* __restrict__ ep,
                                                int* __restrict__ rp, int* __restrict__ cnt,
                                                int cap) {
    __shared__ int hist[256];
    __shared__ int sc[256];
    const int b = blockIdx.x;
    const int tid = threadIdx.x;
    const int s = b * cap;
    int e_ = cursor[b];
    if (e_ > s + cap) e_ = s + cap;
    hist[tid] = 0;
    __syncthreads();
    for (int i = s + tid; i < e_; i += 256)
        atomicAdd(&hist[((unsigned)bpair[i].x) >> 24], 1);
    __syncthreads();
    int v = hist[tid];
    sc[tid] = v;
    __syncthreads();
    for (int off = 1; off < 256; off <<= 1) {
        int t = (tid >= off) ? sc[tid - off] : 0;
        __syncthreads();
        if (tid >= off) sc[tid] += t;
        __syncthreads();
    }
    int excl = sc[tid] - v;
    int gr = (b << BUCK_SHIFT) + tid;
    if (gr < NHG) { rp[gr] = s + excl; cnt[gr] = v; }
    hist[tid] = excl;
    __syncthreads();
    for (int i = s + tid; i < e_; i += 256) {
        int2 p = bpair[i];
        unsigned pk = (unsigned)p.x;
        int pos = atomicAdd(&hist[pk >> 24], 1);
        ep[s + pos] = make_int2((int)(pk & 0xFFFFFFu), p.y);
    }
}

// ---------------- gi spmm body (runs as grid extension of spmm L1) ----------------
static __device__ __forceinline__ void gi_body(const int* __restrict__ rows,
                                               const int* __restrict__ cols,
                                               const float* __restrict__ vals,
                                               const float* __restrict__ ge,
                                               const float* __restrict__ ie,
                                               float* __restrict__ out, int nE,
                                               int blk, int nblk) {
    int lane = threadIdx.x & 63;
    long wslot = (long)blk * 4 + (threadIdx.x >> 6);
    const long nslots = (long)nblk * 4;
    for (long base = wslot * 64; base < nE; base += nslots * 64) {
        long e = base + lane;
        int r = (e < nE) ? rows[e] : 0x7fffffff;
        bool ok = (r < G_N);
        int c = 0;
        float v = 0.f;
        if (ok) { c = cols[e]; v = vals[e]; }
        unsigned long long mask = __ballot(ok);
        while (mask) {
            int srcl = __ffsll(mask) - 1;
            mask &= mask - 1;
            int rr = __shfl(r, srcl, 64);
            int cc = __shfl(c, srcl, 64);
            float vv = __shfl(v, srcl, 64);
            const float* sp = (cc < G_N) ? (ge + (size_t)cc * 64) : (ie + (size_t)(cc - G_N) * 64);
            atomicAdd(&out[(size_t)rr * 64 + lane], vv * sp[lane]);
        }
    }
}

// ---------------- SpMM: 8 rows/wave, 8 lanes x us8 (8 bf16 dims, 16 B/lane) ----------

static __device__ __forceinline__ void spmm_row8(const int2* __restrict__ ep, int s, int n,
                                                 const us8* __restrict__ x16,
                                                 int sub, f32x8& acc) {
#pragma unroll
    for (int t = 0; t < 8; ++t) acc[t] = 0.f;
    for (int i = 0; i < n; i += 8) {
        int2 e[8];
#pragma unroll
        for (int j = 0; j < 8; ++j) {
            int k = i + j;
            int kk = (k < n) ? k : n - 1;   // n>=1 here (loop entered)
            e[j] = ep[s + kk];
            if (k >= n) { e[j].y = 0; e[j].x = 0; }
        }
        us8 xv[8];
#pragma unroll
        for (int j = 0; j < 8; ++j)
            xv[j] = x16[(size_t)e[j].x * 8 + sub];
#pragma unroll
        for (int j = 0; j < 8; ++j) {
            float v = __int_as_float(e[j].y);
#pragma unroll
            for (int t = 0; t < 8; ++t) acc[t] += v * bsf(xv[j][t]);
        }
    }
}

// layers 1/2: 32 rows/block.
// grid ext A [spmmBlocks, spmmBlocks+giBlocks): gi spmm (layer 1 only)
// grid ext B [spmmBlocks+giBlocks, ...): usr_acc += x[ui[b]] (layer 2 only)
__global__ void k_spmm8(const int* __restrict__ rp, const int* __restrict__ cnt,
                        const int2* __restrict__ ep, const us8* __restrict__ x16,
                        us8* __restrict__ out16, float* __restrict__ grp_acc,
                        const int* __restrict__ ui, float* __restrict__ usr_acc,
                        const int* __restrict__ grows, const int* __restrict__ gcols,
                        const float* __restrict__ gvals, const float* __restrict__ ge,
                        const float* __restrict__ ie, float* __restrict__ gi_out, int gnE,
                        int spmmBlocks, int giBlocks) {
    if (blockIdx.x >= spmmBlocks) {
        int ebx = blockIdx.x - spmmBlocks;
        if (ebx < giBlocks) {
            gi_body(grows, gcols, gvals, ge, ie, gi_out, gnE, ebx, giBlocks);
            return;
        }
        int idx = (ebx - giBlocks) * 256 + threadIdx.x;  // < B_N*8
        int b = idx >> 3, d = idx & 7;
        us8 u = x16[(size_t)ui[b] * 8 + d];
        f32x8* g = (f32x8*)usr_acc + ((size_t)b * 8 + d);
        f32x8 t = *g;
#pragma unroll
        for (int j = 0; j < 8; ++j) t[j] += bsf(u[j]);
        *g = t;
        return;
    }
    int wid = threadIdx.x >> 6;
    int lane = threadIdx.x & 63;
    int slot = lane >> 3, sub = lane & 7;
    int r = blockIdx.x * 32 + wid * 8 + slot;
    bool active = (r < NHG);
    int rr = active ? r : NHG - 1;
    int s = rp[rr];
    int n = active ? cnt[rr] : 0;
    f32x8 a;
    spmm_row8(ep, s, n, x16, sub, a);
    if (active) {
        us8 o;
#pragma unroll
        for (int j = 0; j < 8; ++j) o[j] = (unsigned short)bfc(a[j]);
        out16[(size_t)r * 8 + sub] = o;
        if (r >= U_N) {
            f32x8* g = (f32x8*)grp_acc + ((size_t)(r - U_N) * 8 + sub);
            f32x8 t = *g;
#pragma unroll
            for (int j = 0; j < 8; ++j) t[j] += a[j];
            *g = t;
        }
    }
}

// layer 3 targeted; grid ext: usr_acc += x[ui[b]]
__global__ void k_spmm8_final(const int* __restrict__ rp, const int* __restrict__ cnt,
                              const int2* __restrict__ ep, const us8* __restrict__ x16,
                              const int* __restrict__ ui,
                              float* __restrict__ grp_acc, float* __restrict__ usr_acc,
                              int taskBlocks) {
    if (blockIdx.x >= taskBlocks) {
        int idx = (blockIdx.x - taskBlocks) * 256 + threadIdx.x;  // < B_N*8
        int b = idx >> 3, d = idx & 7;
        us8 u = x16[(size_t)ui[b] * 8 + d];
        f32x8* g = (f32x8*)usr_acc + ((size_t)b * 8 + d);
        f32x8 t = *g;
#pragma unroll
        for (int j = 0; j < 8; ++j) t[j] += bsf(u[j]);
        *g = t;
        return;
    }
    int wid = threadIdx.x >> 6;
    int lane = threadIdx.x & 63;
    int slot = lane >> 3, sub = lane & 7;
    int t = blockIdx.x * 32 + wid * 8 + slot;
    bool active = (t < G_N + B_N);
    int tt = active ? t : 0;
    int r = (tt < G_N) ? (U_N + tt) : ui[tt - G_N];
    int s = rp[r];
    int n = active ? cnt[r] : 0;
    f32x8 a;
    spmm_row8(ep, s, n, x16, sub, a);
    if (active) {
        f32x8* g = (tt < G_N) ? ((f32x8*)grp_acc + ((size_t)tt * 8 + sub))
                              : ((f32x8*)usr_acc + ((size_t)(tt - G_N) * 8 + sub));
        f32x8 v = *g;
#pragma unroll
        for (int j = 0; j < 8; ++j) v[j] += a[j];
        *g = v;
    }
}

// ---------------- fused finalize + gather (one wave per batch element) ----------------

__global__ void k_gather_fin(const int* __restrict__ ui, const int* __restrict__ pg,
                             const int* __restrict__ ng, const float* __restrict__ ua,
                             const float* __restrict__ ga, const float* __restrict__ gi_out,
                             const float* __restrict__ gg_part,
                             const float* __restrict__ hw, const float* __restrict__ hb,
                             const float* __restrict__ lw, const float* __restrict__ lb,
                             const float* __restrict__ ow, const float* __restrict__ ob,
                             const float* __restrict__ ue, const float* __restrict__ ge,
                             float* __restrict__ out) {
    int wid = threadIdx.x >> 6, lane = threadIdx.x & 63;
    int b = blockIdx.x * 4 + wid;  // B_N = 4*2048, exact
    const int S = B_N * 64;
    int u = ui[b], p = pg[b], q = ng[b];
    int idx = b * 64 + lane;
    out[idx]         = ua[idx] * 0.25f;
    out[3 * S + idx] = ue[(size_t)u * 64 + lane];
    out[4 * S + idx] = ge[(size_t)p * 64 + lane];
    out[5 * S + idx] = ge[(size_t)q * 64 + lane];
    const size_t SS = (size_t)G_N * 64;
    float hwv = hw[lane], lwv = lw[lane], owv = ow[lane];
    float hb0 = hb[0], lb0 = lb[0], ob0 = ob[0];
#pragma unroll
    for (int which = 0; which < 2; ++which) {
        int g = which ? q : p;
        size_t o = (size_t)g * 64 + lane;
        float hgv = ga[o] * 0.25f;
        float giv = gi_out[o];
        float ggv = 0.f;
#pragma unroll
        for (int k = 0; k < GG_SPLIT; ++k) ggv += gg_part[k * SS + o];
        float d1 = hgv * hwv, d2 = giv * lwv, d3 = ggv * owv;
#pragma unroll
        for (int off2 = 32; off2; off2 >>= 1) {
            d1 += __shfl_xor(d1, off2, 64);
            d2 += __shfl_xor(d2, off2, 64);
            d3 += __shfl_xor(d3, off2, 64);
        }
        float val = sigmoidf_(d1 + hb0) * hgv + sigmoidf_(d2 + lb0) * giv
                  + sigmoidf_(d3 + ob0) * ggv;
        out[(which ? 2 * S : S) + idx] = val;
    }
}

extern "C" void kernel_launch(void* const* d_in, const int* in_sizes, int n_in,
                              void* d_out, int out_size, void* d_ws, size_t ws_size,
                              hipStream_t stream) {
    const int*   ui        = (const int*)d_in[0];
    const int*   pg        = (const int*)d_in[1];
    const int*   ng        = (const int*)d_in[2];
    const int*   hg_rows   = (const int*)d_in[3];
    const int*   hg_cols   = (const int*)d_in[4];
    const float* hg_vals   = (const float*)d_in[5];
    const int*   gi_rows   = (const int*)d_in[6];
    const int*   gi_cols   = (const int*)d_in[7];
    const float* gi_vals   = (const float*)d_in[8];
    const float* gg_graph  = (const float*)d_in[9];
    const float* user_emb  = (const float*)d_in[10];
    const float* item_emb  = (const float*)d_in[11];
    const float* group_emb = (const float*)d_in[12];
    const float* hyper_w   = (const float*)d_in[13];
    const float* hyper_b   = (const float*)d_in[14];
    const float* lgcn_w    = (const float*)d_in[15];
    const float* lgcn_b    = (const float*)d_in[16];
    const float* ovl_w     = (const float*)d_in[17];
    const float* ovl_b     = (const float*)d_in[18];
    const int E_HG = in_sizes[3];
    const int E_GI = in_sizes[6];

    const int nblkA = (E_HG + ACHUNK - 1) / ACHUNK;
    int cap = (E_HG + NBUCK - 1) / NBUCK;
    cap = cap + cap / 4 + 64;
    cap = (cap + 63) & ~63;

    // ---- workspace layout (~135 MB; ws is ~1.6 GB) ----
    char* ws = (char*)d_ws;
    size_t off = 0;
    auto alloc = [&](size_t bytes) -> char* {
        char* p = ws + off;
        off += (bytes + 255) & ~(size_t)255;
        return p;
    };
    int*   cursor  = (int*)alloc((size_t)NBUCK * 4);
    int2*  bpair   = (int2*)alloc((size_t)NBUCK * cap * 8);
    int2*  ep      = (int2*)alloc((size_t)NBUCK * cap * 8 + 1024);
    int*   rp      = (int*)alloc((size_t)NHG * 4);
    int*   cnt     = (int*)alloc((size_t)NHG * 4);
    __hip_bfloat16* curA = (__hip_bfloat16*)alloc((size_t)NHG * 64 * 2);
    __hip_bfloat16* curB = (__hip_bfloat16*)alloc((size_t)NHG * 64 * 2);
    float* grp_acc = (float*)alloc((size_t)G_N * 64 * 4);
    float* gi_out  = (float*)alloc((size_t)G_N * 64 * 4);
    float* usr_acc = (float*)alloc((size_t)B_N * 64 * 4);
    short* Bfrag   = (short*)alloc((size_t)GG_KC4 * 4 * 64 * 8 * 2);
    float* gg_part = (float*)alloc((size_t)GG_SPLIT * GG_K * 64 * 4);
    (void)ws_size; (void)n_in; (void)out_size;

    // ---- P1: bfrag (316 kc, zero-filled tail) + cursor init ----
    k_phase1<<<GG_KC4 + 4, 256, 0, stream>>>(group_emb, Bfrag, cursor, cap, GG_KC4);

    // ---- P2: bscatter || gg_mfma(LDS) || cvt || ua/ga init || gi zero ----
    const int ggB  = GG_STRIPES * GG_SPLIT;  // 1256
    const int cvtB = (NHG * 16) / 256;       // 13125
    const int uaB  = (B_N * 64) / 256;       // 2048
    const int gaB  = (G_N * 64) / 256;       // 2500
    const int gzB  = (G_N * 64) / 256;       // 2500
    k_phase2<<<nblkA + ggB + cvtB + uaB + gaB + gzB, 256, 0, stream>>>(
        hg_rows, hg_cols, hg_vals, cursor, bpair, E_HG, cap,
        gg_graph, Bfrag, gg_part,
        (const float4*)user_emb, (const float4*)group_emb, (ushort4*)curB, ui,
        usr_acc, grp_acc, gi_out, nblkA, ggB, cvtB, uaB, gaB);

    // ---- P3: bcsr only ----
    k_phase3<<<NBUCK, 256, 0, stream>>>(cursor, bpair, ep, rp, cnt, cap);

    const int spmmB = (NHG + 31) / 32;       // 6563
    const int uaExt = (B_N * 8) / 256;       // 256
    const int giB   = 1536;

    // P4: layer 1: curB -> curA (grp_acc fused) || gi spmm (independent, overlapped)
    k_spmm8<<<spmmB + giB, 256, 0, stream>>>(rp, cnt, ep, (const us8*)curB,
                                             (us8*)curA, grp_acc, nullptr, nullptr,
                                             gi_rows, gi_cols, gi_vals, group_emb,
                                             item_emb, gi_out, E_GI, spmmB, giB);
    // P5: layer 2: curA -> curB (grp_acc fused; ext: usr_acc += curA[ui])
    k_spmm8<<<spmmB + uaExt, 256, 0, stream>>>(rp, cnt, ep, (const us8*)curA,
                                               (us8*)curB, grp_acc, ui, usr_acc,
                                               nullptr, nullptr, nullptr, nullptr,
                                               nullptr, nullptr, 0, spmmB, 0);
    // P6: layer 3 targeted; ext: usr_acc += curB[ui]
    const int taskB = (G_N + B_N + 31) / 32;  // 569
    k_spmm8_final<<<taskB + uaExt, 256, 0, stream>>>(rp, cnt, ep, (const us8*)curB, ui,
                                                     grp_acc, usr_acc, taskB);

    // P7: fused finalize + gather
    k_gather_fin<<<B_N / 4, 256, 0, stream>>>(ui, pg, ng, usr_acc, grp_acc, gi_out, gg_part,
                                              hyper_w, hyper_b, lgcn_w, lgcn_b, ovl_w, ovl_b,
                                              user_emb, group_emb, (float*)d_out);
}

// Round 19
// 394.944 us; speedup vs baseline: 1.0252x; 1.0252x over previous
//
#include <hip/hip_runtime.h>
#include <hip/hip_bf16.h>

#define U_N 200000
#define I_N 100000
#define G_N 10000
#define B_N 8192
#define NHG (U_N + G_N)   /* 210000 */
#define GG_K 10000
#define GG_STRIPES 157    /* ceil(10000/64) row stripes */
#define GG_SPLIT 8
#define GG_SC_TOT 79      /* ceil(10000/128) super-chunks */
#define GG_KC4 316        /* Bfrag kc count = 4*GG_SC_TOT */
#define ROWSTR 136        /* LDS row stride in bf16: 128 + 8 pad */

#define BUCK_SHIFT 8
#define BUCK_ROWS 256
#define NBUCK 821         /* ceil(NHG/256) */
#define ACHUNK 12288      /* edges per partition block */

typedef __attribute__((ext_vector_type(8))) short bf16x8;
typedef __attribute__((ext_vector_type(4))) float f32x4;
typedef __attribute__((ext_vector_type(8))) float f32x8;
typedef __attribute__((ext_vector_type(8))) unsigned short us8;

static __device__ __forceinline__ float sigmoidf_(float x) {
    return 1.0f / (1.0f + __expf(-x));
}

// f32 -> bf16 bits, round-to-nearest-even
static __device__ __forceinline__ unsigned bfc(float x) {
    unsigned u = __float_as_uint(x);
    return (u + 0x7fffu + ((u >> 16) & 1u)) >> 16;
}
static __device__ __forceinline__ float bsf(unsigned short u) {
    return __uint_as_float((unsigned)u << 16);
}

// ================= PHASE 1: bfrag + cursor init =================
__global__ void k_phase1(const float* __restrict__ ge, short* __restrict__ Bfrag,
                         int* __restrict__ cursor, int cap, int bfB) {
    int bx = blockIdx.x;
    if (bx < bfB) {
        int t = bx * 256 + threadIdx.x;  // < 316*4*64 exactly
        int l = t & 63;
        int ct = (t >> 6) & 3;
        int kc = t >> 8;
        int j = ct * 16 + (l & 15);
        int kb = kc * 32 + (l >> 4) * 8;
        bf16x8 pack;
#pragma unroll
        for (int e = 0; e < 8; ++e) {
            int k = kb + e;
            float f = (k < GG_K) ? ge[(size_t)k * 64 + j] : 0.f;
            pack[e] = (short)bfc(f);
        }
        *(bf16x8*)(Bfrag + (size_t)t * 8) = pack;
        return;
    }
    int b = (bx - bfB) * 256 + threadIdx.x;
    if (b < NBUCK) cursor[b] = b * cap;
}

// ================= PHASE 2: bscatter || gg_mfma(LDS-staged) || cvt || inits ==========

static __device__ __forceinline__ void bscatter_body(const int* __restrict__ rows,
                                                     const int* __restrict__ cols,
                                                     const float* __restrict__ vals,
                                                     int* __restrict__ cursor,
                                                     int2* __restrict__ bpair,
                                                     int nE, int cap, int blk) {
    __shared__ int h[NBUCK];
    __shared__ int base[NBUCK];
    for (int i = threadIdx.x; i < NBUCK; i += 256) h[i] = 0;
    __syncthreads();
    int s = blk * ACHUNK;
    int end = s + ACHUNK; if (end > nE) end = nE;
    for (int e = s + threadIdx.x; e < end; e += 256)
        atomicAdd(&h[rows[e] >> BUCK_SHIFT], 1);
    __syncthreads();
    for (int i = threadIdx.x; i < NBUCK; i += 256) {
        int c = h[i];
        base[i] = c ? atomicAdd(&cursor[i], c) : 0;
        h[i] = 0;
    }
    __syncthreads();
    for (int e = s + threadIdx.x; e < end; e += 256) {
        int r = rows[e];
        int b = r >> BUCK_SHIFT;
        int pos = base[b] + atomicAdd(&h[b], 1);
        if (pos < (b + 1) * cap)
            bpair[pos] = make_int2(((r & (BUCK_ROWS - 1)) << 24) | cols[e],
                                   __float_as_int(vals[e]));
    }
}

// gg with LDS-staged A: contiguous 512B global reads per 32-lane group.
static __device__ __forceinline__ void gg_mfma_body(const float* __restrict__ A,
                                                    const short* __restrict__ Bfrag,
                                                    float* __restrict__ part, int blk) {
    __shared__ short lds_a[64 * ROWSTR];  // 17408 B
    const int stripe = blk % GG_STRIPES;
    const int ks = blk / GG_STRIPES;            // 0..7
    const int sc0 = ks * 10;
    const int sc1 = (ks == 7) ? GG_SC_TOT : sc0 + 10;
    const int tid = threadIdx.x;
    const int w = tid >> 6, l = tid & 63;
    const int r0w = stripe * 64 + w * 16;
    const int srow = tid >> 5;                  // 0..7
    const int scol = (tid & 31) * 4;            // float offset within 128
    f32x4 acc0 = {0.f, 0.f, 0.f, 0.f}, acc1 = acc0, acc2 = acc0, acc3 = acc0;
    for (int sc = sc0; sc < sc1; ++sc) {
        __syncthreads();
#pragma unroll
        for (int pass = 0; pass < 8; ++pass) {
            int rl = pass * 8 + srow;
            int rg = stripe * 64 + rl; if (rg > GG_K - 1) rg = GG_K - 1;
            int kg = sc * 128 + scol;           // multiple of 4; no f4 straddle at 10000
            float4 a = {0.f, 0.f, 0.f, 0.f};
            if (kg < GG_K) a = *(const float4*)(A + (size_t)rg * GG_K + kg);
            ushort4 o;
            o.x = (unsigned short)bfc(a.x); o.y = (unsigned short)bfc(a.y);
            o.z = (unsigned short)bfc(a.z); o.w = (unsigned short)bfc(a.w);
            *(ushort4*)(lds_a + rl * ROWSTR + scol) = o;
        }
        __syncthreads();
#pragma unroll
        for (int q = 0; q < 4; ++q) {
            int kc = sc * 4 + q;
            bf16x8 af = *(const bf16x8*)(lds_a + (w * 16 + (l & 15)) * ROWSTR
                                         + q * 32 + (l >> 4) * 8);
            const bf16x8* bp = (const bf16x8*)(Bfrag + (size_t)kc * 4 * 64 * 8);
            bf16x8 b0 = bp[0 * 64 + l];
            bf16x8 b1 = bp[1 * 64 + l];
            bf16x8 b2 = bp[2 * 64 + l];
            bf16x8 b3 = bp[3 * 64 + l];
            acc0 = __builtin_amdgcn_mfma_f32_16x16x32_bf16(af, b0, acc0, 0, 0, 0);
            acc1 = __builtin_amdgcn_mfma_f32_16x16x32_bf16(af, b1, acc1, 0, 0, 0);
            acc2 = __builtin_amdgcn_mfma_f32_16x16x32_bf16(af, b2, acc2, 0, 0, 0);
            acc3 = __builtin_amdgcn_mfma_f32_16x16x32_bf16(af, b3, acc3, 0, 0, 0);
        }
    }
    float* po = part + (size_t)ks * GG_K * 64;
    const int orow0 = r0w + (l >> 4) * 4;
    const int ocol = l & 15;
#pragma unroll
    for (int reg = 0; reg < 4; ++reg) {
        int orow = orow0 + reg;
        if (orow < GG_K) {
            float* q = po + (size_t)orow * 64 + ocol;
            q[0]  = acc0[reg];
            q[16] = acc1[reg];
            q[32] = acc2[reg];
            q[48] = acc3[reg];
        }
    }
}

// segments: [0,bsB) bscatter | [+ggB) gg | [+cvtB) cvt | [+uaB) ua init
//         | [+gaB) grp_acc init | gi zero
__global__ __launch_bounds__(256) void k_phase2(
    const int* __restrict__ rows, const int* __restrict__ cols,
    const float* __restrict__ vals, int* __restrict__ cursor,
    int2* __restrict__ bpair, int nE, int cap,
    const float* __restrict__ A, const short* __restrict__ Bfrag,
    float* __restrict__ part,
    const float4* __restrict__ ue4, const float4* __restrict__ ge4,
    ushort4* __restrict__ out4, const int* __restrict__ ui,
    float* __restrict__ ua, float* __restrict__ grp_acc, float* __restrict__ gi_out,
    int bsB, int ggB, int cvtB, int uaB, int gaB) {
    int bx = blockIdx.x;
    if (bx < bsB) { bscatter_body(rows, cols, vals, cursor, bpair, nE, cap, bx); return; }
    bx -= bsB;
    if (bx < ggB) { gg_mfma_body(A, Bfrag, part, bx); return; }
    bx -= ggB;
    if (bx < cvtB) {
        int i = bx * 256 + threadIdx.x;  // < NHG*16 exactly
        float4 f = (i < U_N * 16) ? ue4[i] : ge4[i - U_N * 16];
        ushort4 o;
        o.x = (unsigned short)bfc(f.x);
        o.y = (unsigned short)bfc(f.y);
        o.z = (unsigned short)bfc(f.z);
        o.w = (unsigned short)bfc(f.w);
        out4[i] = o;
        return;
    }
    bx -= cvtB;
    if (bx < uaB) {
        int idx = bx * 256 + threadIdx.x;  // < B_N*64
        int b = idx >> 6, d = idx & 63;
        ua[idx] = ((const float*)ue4)[(size_t)ui[b] * 64 + d];
        return;
    }
    bx -= uaB;
    if (bx < gaB) {
        int idx = bx * 256 + threadIdx.x;  // < G_N*64
        grp_acc[idx] = ((const float*)ge4)[idx];
        return;
    }
    bx -= gaB;
    int idx = bx * 256 + threadIdx.x;
    gi_out[idx] = 0.f;
}

// ================= PHASE 3: bcsr || gi_spmm =================

static __device__ __forceinline__ void bcsr_body(const int* __restrict__ cursor,
                                                 const int2* __restrict__ bpair,
                                                 int2* __restrict__ ep,
                                                 int* __restrict__ rp, int* __restrict__ cnt,
                                                 int cap, int b) {
    __shared__ int hist[256];
    __shared__ int sc[256];
    const int tid = threadIdx.x;
    const int s = b * cap;
    int e_ = cursor[b];
    if (e_ > s + cap) e_ = s + cap;
    hist[tid] = 0;
    __syncthreads();
    for (int i = s + tid; i < e_; i += 256)
        atomicAdd(&hist[((unsigned)bpair[i].x) >> 24], 1);
    __syncthreads();
    int v = hist[tid];
    sc[tid] = v;
    __syncthreads();
    for (int off = 1; off < 256; off <<= 1) {
        int t = (tid >= off) ? sc[tid - off] : 0;
        __syncthreads();
        if (tid >= off) sc[tid] += t;
        __syncthreads();
    }
    int excl = sc[tid] - v;
    int gr = (b << BUCK_SHIFT) + tid;
    if (gr < NHG) { rp[gr] = s + excl; cnt[gr] = v; }
    hist[tid] = excl;
    __syncthreads();
    for (int i = s + tid; i < e_; i += 256) {
        int2 p = bpair[i];
        unsigned pk = (unsigned)p.x;
        int pos = atomicAdd(&hist[pk >> 24], 1);
        ep[s + pos] = make_int2((int)(pk & 0xFFFFFFu), p.y);
    }
}

static __device__ __forceinline__ void gi_body(const int* __restrict__ rows,
                                               const int* __restrict__ cols,
                                               const float* __restrict__ vals,
                                               const float* __restrict__ ge,
                                               const float* __restrict__ ie,
                                               float* __restrict__ out, int nE,
                                               int blk, int nblk) {
    int lane = threadIdx.x & 63;
    long wslot = (long)blk * 4 + (threadIdx.x >> 6);
    const long nslots = (long)nblk * 4;
    for (long base = wslot * 64; base < nE; base += nslots * 64) {
        long e = base + lane;
        int r = (e < nE) ? rows[e] : 0x7fffffff;
        bool ok = (r < G_N);
        int c = 0;
        float v = 0.f;
        if (ok) { c = cols[e]; v = vals[e]; }
        unsigned long long mask = __ballot(ok);
        while (mask) {
            int srcl = __ffsll(mask) - 1;
            mask &= mask - 1;
            int rr = __shfl(r, srcl, 64);
            int cc = __shfl(c, srcl, 64);
            float vv = __shfl(v, srcl, 64);
            const float* sp = (cc < G_N) ? (ge + (size_t)cc * 64) : (ie + (size_t)(cc - G_N) * 64);
            atomicAdd(&out[(size_t)rr * 64 + lane], vv * sp[lane]);
        }
    }
}

__global__ __launch_bounds__(256) void k_phase3(const int* __restrict__ cursor,
                                                const int2* __restrict__ bpair,
                                                int2* __restrict__ ep,
                                                int* __restrict__ rp, int* __restrict__ cnt,
                                                int cap,
                                                const int* __restrict__ grows,
                                                const int* __restrict__ gcols,
                                                const float* __restrict__ gvals,
                                                const float* __restrict__ ge,
                                                const float* __restrict__ ie,
                                                float* __restrict__ gi_out, int gnE, int giB) {
    if (blockIdx.x < NBUCK)
        bcsr_body(cursor, bpair, ep, rp, cnt, cap, blockIdx.x);
    else
        gi_body(grows, gcols, gvals, ge, ie, gi_out, gnE, blockIdx.x - NBUCK, giB);
}

// ---------------- SpMM: 8 rows/wave, 8 lanes x us8 (8 bf16 dims, 16 B/lane) ----------

static __device__ __forceinline__ void spmm_row8(const int2* __restrict__ ep, int s, int n,
                                                 const us8* __restrict__ x16,
                                                 int sub, f32x8& acc) {
#pragma unroll
    for (int t = 0; t < 8; ++t) acc[t] = 0.f;
    for (int i = 0; i < n; i += 8) {
        int2 e[8];
#pragma unroll
        for (int j = 0; j < 8; ++j) {
            int k = i + j;
            int kk = (k < n) ? k : n - 1;   // n>=1 here (loop entered)
            e[j] = ep[s + kk];
            if (k >= n) { e[j].y = 0; e[j].x = 0; }
        }
        us8 xv[8];
#pragma unroll
        for (int j = 0; j < 8; ++j)
            xv[j] = x16[(size_t)e[j].x * 8 + sub];
#pragma unroll
        for (int j = 0; j < 8; ++j) {
            float v = __int_as_float(e[j].y);
#pragma unroll
            for (int t = 0; t < 8; ++t) acc[t] += v * bsf(xv[j][t]);
        }
    }
}

// layers 1/2: 32 rows/block; grid ext: usr_acc += x[ui[b]]
__global__ void k_spmm8(const int* __restrict__ rp, const int* __restrict__ cnt,
                        const int2* __restrict__ ep, const us8* __restrict__ x16,
                        us8* __restrict__ out16, float* __restrict__ grp_acc,
                        const int* __restrict__ ui, float* __restrict__ usr_acc,
                        int spmmBlocks) {
    if (blockIdx.x >= spmmBlocks) {
        int idx = (blockIdx.x - spmmBlocks) * 256 + threadIdx.x;  // < B_N*8
        int b = idx >> 3, d = idx & 7;
        us8 u = x16[(size_t)ui[b] * 8 + d];
        f32x8* g = (f32x8*)usr_acc + ((size_t)b * 8 + d);
        f32x8 t = *g;
#pragma unroll
        for (int j = 0; j < 8; ++j) t[j] += bsf(u[j]);
        *g = t;
        return;
    }
    int wid = threadIdx.x >> 6;
    int lane = threadIdx.x & 63;
    int slot = lane >> 3, sub = lane & 7;
    int r = blockIdx.x * 32 + wid * 8 + slot;
    bool active = (r < NHG);
    int rr = active ? r : NHG - 1;
    int s = rp[rr];
    int n = active ? cnt[rr] : 0;
    f32x8 a;
    spmm_row8(ep, s, n, x16, sub, a);
    if (active) {
        us8 o;
#pragma unroll
        for (int j = 0; j < 8; ++j) o[j] = (unsigned short)bfc(a[j]);
        out16[(size_t)r * 8 + sub] = o;
        if (r >= U_N) {
            f32x8* g = (f32x8*)grp_acc + ((size_t)(r - U_N) * 8 + sub);
            f32x8 t = *g;
#pragma unroll
            for (int j = 0; j < 8; ++j) t[j] += a[j];
            *g = t;
        }
    }
}

// layer 3 targeted; grid ext: usr_acc += x[ui[b]]
__global__ void k_spmm8_final(const int* __restrict__ rp, const int* __restrict__ cnt,
                              const int2* __restrict__ ep, const us8* __restrict__ x16,
                              const int* __restrict__ ui,
                              float* __restrict__ grp_acc, float* __restrict__ usr_acc,
                              int taskBlocks) {
    if (blockIdx.x >= taskBlocks) {
        int idx = (blockIdx.x - taskBlocks) * 256 + threadIdx.x;  // < B_N*8
        int b = idx >> 3, d = idx & 7;
        us8 u = x16[(size_t)ui[b] * 8 + d];
        f32x8* g = (f32x8*)usr_acc + ((size_t)b * 8 + d);
        f32x8 t = *g;
#pragma unroll
        for (int j = 0; j < 8; ++j) t[j] += bsf(u[j]);
        *g = t;
        return;
    }
    int wid = threadIdx.x >> 6;
    int lane = threadIdx.x & 63;
    int slot = lane >> 3, sub = lane & 7;
    int t = blockIdx.x * 32 + wid * 8 + slot;
    bool active = (t < G_N + B_N);
    int tt = active ? t : 0;
    int r = (tt < G_N) ? (U_N + tt) : ui[tt - G_N];
    int s = rp[r];
    int n = active ? cnt[r] : 0;
    f32x8 a;
    spmm_row8(ep, s, n, x16, sub, a);
    if (active) {
        f32x8* g = (tt < G_N) ? ((f32x8*)grp_acc + ((size_t)tt * 8 + sub))
                              : ((f32x8*)usr_acc + ((size_t)(tt - G_N) * 8 + sub));
        f32x8 v = *g;
#pragma unroll
        for (int j = 0; j < 8; ++j) v[j] += a[j];
        *g = v;
    }
}

// ---------------- fused finalize + gather (one wave per batch element) ----------------

__global__ void k_gather_fin(const int* __restrict__ ui, const int* __restrict__ pg,
                             const int* __restrict__ ng, const float* __restrict__ ua,
                             const float* __restrict__ ga, const float* __restrict__ gi_out,
                             const float* __restrict__ gg_part,
                             const float* __restrict__ hw, const float* __restrict__ hb,
                             const float* __restrict__ lw, const float* __restrict__ lb,
                             const float* __restrict__ ow, const float* __restrict__ ob,
                             const float* __restrict__ ue, const float* __restrict__ ge,
                             float* __restrict__ out) {
    int wid = threadIdx.x >> 6, lane = threadIdx.x & 63;
    int b = blockIdx.x * 4 + wid;  // B_N = 4*2048, exact
    const int S = B_N * 64;
    int u = ui[b], p = pg[b], q = ng[b];
    int idx = b * 64 + lane;
    out[idx]         = ua[idx] * 0.25f;
    out[3 * S + idx] = ue[(size_t)u * 64 + lane];
    out[4 * S + idx] = ge[(size_t)p * 64 + lane];
    out[5 * S + idx] = ge[(size_t)q * 64 + lane];
    const size_t SS = (size_t)G_N * 64;
    float hwv = hw[lane], lwv = lw[lane], owv = ow[lane];
    float hb0 = hb[0], lb0 = lb[0], ob0 = ob[0];
#pragma unroll
    for (int which = 0; which < 2; ++which) {
        int g = which ? q : p;
        size_t o = (size_t)g * 64 + lane;
        float hgv = ga[o] * 0.25f;
        float giv = gi_out[o];
        float ggv = 0.f;
#pragma unroll
        for (int k = 0; k < GG_SPLIT; ++k) ggv += gg_part[k * SS + o];
        float d1 = hgv * hwv, d2 = giv * lwv, d3 = ggv * owv;
#pragma unroll
        for (int off2 = 32; off2; off2 >>= 1) {
            d1 += __shfl_xor(d1, off2, 64);
            d2 += __shfl_xor(d2, off2, 64);
            d3 += __shfl_xor(d3, off2, 64);
        }
        float val = sigmoidf_(d1 + hb0) * hgv + sigmoidf_(d2 + lb0) * giv
                  + sigmoidf_(d3 + ob0) * ggv;
        out[(which ? 2 * S : S) + idx] = val;
    }
}

extern "C" void kernel_launch(void* const* d_in, const int* in_sizes, int n_in,
                              void* d_out, int out_size, void* d_ws, size_t ws_size,
                              hipStream_t stream) {
    const int*   ui        = (const int*)d_in[0];
    const int*   pg        = (const int*)d_in[1];
    const int*   ng        = (const int*)d_in[2];
    const int*   hg_rows   = (const int*)d_in[3];
    const int*   hg_cols   = (const int*)d_in[4];
    const float* hg_vals   = (const float*)d_in[5];
    const int*   gi_rows   = (const int*)d_in[6];
    const int*   gi_cols   = (const int*)d_in[7];
    const float* gi_vals   = (const float*)d_in[8];
    const float* gg_graph  = (const float*)d_in[9];
    const float* user_emb  = (const float*)d_in[10];
    const float* item_emb  = (const float*)d_in[11];
    const float* group_emb = (const float*)d_in[12];
    const float* hyper_w   = (const float*)d_in[13];
    const float* hyper_b   = (const float*)d_in[14];
    const float* lgcn_w    = (const float*)d_in[15];
    const float* lgcn_b    = (const float*)d_in[16];
    const float* ovl_w     = (const float*)d_in[17];
    const float* ovl_b     = (const float*)d_in[18];
    const int E_HG = in_sizes[3];
    const int E_GI = in_sizes[6];

    const int nblkA = (E_HG + ACHUNK - 1) / ACHUNK;
    int cap = (E_HG + NBUCK - 1) / NBUCK;
    cap = cap + cap / 4 + 64;
    cap = (cap + 63) & ~63;

    // ---- workspace layout (~135 MB; ws is ~1.6 GB) ----
    char* ws = (char*)d_ws;
    size_t off = 0;
    auto alloc = [&](size_t bytes) -> char* {
        char* p = ws + off;
        off += (bytes + 255) & ~(size_t)255;
        return p;
    };
    int*   cursor  = (int*)alloc((size_t)NBUCK * 4);
    int2*  bpair   = (int2*)alloc((size_t)NBUCK * cap * 8);
    int2*  ep      = (int2*)alloc((size_t)NBUCK * cap * 8 + 1024);
    int*   rp      = (int*)alloc((size_t)NHG * 4);
    int*   cnt     = (int*)alloc((size_t)NHG * 4);
    __hip_bfloat16* curA = (__hip_bfloat16*)alloc((size_t)NHG * 64 * 2);
    __hip_bfloat16* curB = (__hip_bfloat16*)alloc((size_t)NHG * 64 * 2);
    float* grp_acc = (float*)alloc((size_t)G_N * 64 * 4);
    float* gi_out  = (float*)alloc((size_t)G_N * 64 * 4);
    float* usr_acc = (float*)alloc((size_t)B_N * 64 * 4);
    short* Bfrag   = (short*)alloc((size_t)GG_KC4 * 4 * 64 * 8 * 2);
    float* gg_part = (float*)alloc((size_t)GG_SPLIT * GG_K * 64 * 4);
    (void)ws_size; (void)n_in; (void)out_size;

    // ---- P1: bfrag (316 kc, zero-filled tail) + cursor init ----
    k_phase1<<<GG_KC4 + 4, 256, 0, stream>>>(group_emb, Bfrag, cursor, cap, GG_KC4);

    // ---- P2: bscatter || gg_mfma(LDS) || cvt || ua/ga init || gi zero ----
    const int ggB  = GG_STRIPES * GG_SPLIT;  // 1256
    const int cvtB = (NHG * 16) / 256;       // 13125
    const int uaB  = (B_N * 64) / 256;       // 2048
    const int gaB  = (G_N * 64) / 256;       // 2500
    const int gzB  = (G_N * 64) / 256;       // 2500
    k_phase2<<<nblkA + ggB + cvtB + uaB + gaB + gzB, 256, 0, stream>>>(
        hg_rows, hg_cols, hg_vals, cursor, bpair, E_HG, cap,
        gg_graph, Bfrag, gg_part,
        (const float4*)user_emb, (const float4*)group_emb, (ushort4*)curB, ui,
        usr_acc, grp_acc, gi_out, nblkA, ggB, cvtB, uaB, gaB);

    // ---- P3: bcsr || gi_spmm ----
    const int giB = 2048;
    k_phase3<<<NBUCK + giB, 256, 0, stream>>>(cursor, bpair, ep, rp, cnt, cap,
                                              gi_rows, gi_cols, gi_vals,
                                              group_emb, item_emb, gi_out, E_GI, giB);

    const int spmmB = (NHG + 31) / 32;       // 6563
    const int uaExt = (B_N * 8) / 256;       // 256

    // P4: layer 1: curB -> curA (grp_acc fused)
    k_spmm8<<<spmmB, 256, 0, stream>>>(rp, cnt, ep, (const us8*)curB,
                                       (us8*)curA, grp_acc, nullptr, nullptr, spmmB);
    // P5: layer 2: curA -> curB (grp_acc fused; ext: usr_acc += curA[ui])
    k_spmm8<<<spmmB + uaExt, 256, 0, stream>>>(rp, cnt, ep, (const us8*)curA,
                                               (us8*)curB, grp_acc, ui, usr_acc, spmmB);
    // P6: layer 3 targeted; ext: usr_acc += curB[ui]
    const int taskB = (G_N + B_N + 31) / 32;  // 569
    k_spmm8_final<<<taskB + uaExt, 256, 0, stream>>>(rp, cnt, ep, (const us8*)curB, ui,
                                                     grp_acc, usr_acc, taskB);

    // P7: fused finalize + gather
    k_gather_fin<<<B_N / 4, 256, 0, stream>>>(ui, pg, ng, usr_acc, grp_acc, gi_out, gg_part,
                                              hyper_w, hyper_b, lgcn_w, lgcn_b, ovl_w, ovl_b,
                                              user_emb, group_emb, (float*)d_out);
}